// Round 1
// baseline (1778.392 us; speedup 1.0000x reference)
//
#include <hip/hip_runtime.h>

#define NN 50000
#define EE 800000
#define ETOT (EE + NN)
#define GG 256
#define LL 3
#define HH 4
#define DD 128

// Monotone float<->uint mapping so unsigned atomicMax == float max.
__device__ __forceinline__ unsigned enc_f(float f) {
  unsigned b = __float_as_uint(f);
  return (b & 0x80000000u) ? ~b : (b | 0x80000000u);
}
__device__ __forceinline__ float dec_f(unsigned u) {
  unsigned b = (u & 0x80000000u) ? (u & 0x7FFFFFFFu) : ~u;
  return __uint_as_float(b);
}

// h = A[N,128] @ W[128,128]; 32-row tile per block, full W staged in LDS.
__global__ __launch_bounds__(256) void gemm_k(const float* __restrict__ A,
                                              const float* __restrict__ Wl,
                                              float* __restrict__ Hh) {
  __shared__ float sW[128 * 128];   // 64 KB
  __shared__ float sA[32][128];     // 16 KB
  int tid = threadIdx.x;
  for (int i = tid; i < 128 * 128; i += 256) sW[i] = Wl[i];
  int row0 = blockIdx.x * 32;
  for (int i = tid; i < 32 * 128; i += 256) {
    int r = i >> 7, c = i & 127;
    int gr = row0 + r;
    sA[r][c] = (gr < NN) ? A[(size_t)gr * DD + c] : 0.f;
  }
  __syncthreads();
  int tc = tid & 31;   // 4 cols each: 4*tc..4*tc+3
  int tr = tid >> 5;   // 4 rows each: 4*tr..4*tr+3
  float acc[4][4] = {};
  for (int k = 0; k < 128; ++k) {
    float4 w = *(const float4*)&sW[k * 128 + tc * 4];
    float a[4];
#pragma unroll
    for (int r = 0; r < 4; ++r) a[r] = sA[tr * 4 + r][k];
#pragma unroll
    for (int r = 0; r < 4; ++r) {
      acc[r][0] += a[r] * w.x;
      acc[r][1] += a[r] * w.y;
      acc[r][2] += a[r] * w.z;
      acc[r][3] += a[r] * w.w;
    }
  }
#pragma unroll
  for (int r = 0; r < 4; ++r) {
    int gr = row0 + tr * 4 + r;
    if (gr < NN) {
      float4 o = {acc[r][0], acc[r][1], acc[r][2], acc[r][3]};
      *(float4*)&Hh[(size_t)gr * DD + tc * 4] = o;
    }
  }
}

// Per-node attention logits al_s[n][h], al_d[n][h]; one wave per node.
__global__ __launch_bounds__(256) void al_k(const float* __restrict__ Hh,
                                            const float* __restrict__ asrc,
                                            const float* __restrict__ adst,
                                            float* __restrict__ al_s,
                                            float* __restrict__ al_d) {
  int wave = threadIdx.x >> 6;
  int lane = threadIdx.x & 63;
  int n = blockIdx.x * 4 + wave;
  if (n >= NN) return;
  int f0 = lane, f1 = lane + 64;
  float h0 = Hh[(size_t)n * DD + f0], h1 = Hh[(size_t)n * DD + f1];
  float s0 = h0 * asrc[f0], s1 = h1 * asrc[f1];
  float d0 = h0 * adst[f0], d1 = h1 * adst[f1];
#pragma unroll
  for (int off = 16; off; off >>= 1) {
    s0 += __shfl_xor(s0, off);
    s1 += __shfl_xor(s1, off);
    d0 += __shfl_xor(d0, off);
    d1 += __shfl_xor(d1, off);
  }
  if ((lane & 31) == 0) {
    int hg = lane >> 5;  // 0 or 1
    al_s[n * 4 + hg] = s0;
    al_s[n * 4 + 2 + hg] = s1;
    al_d[n * 4 + hg] = d0;
    al_d[n * 4 + 2 + hg] = d1;
  }
}

__device__ __forceinline__ void edge_sd(const int* __restrict__ ei, int e, int& s, int& d) {
  if (e < EE) { s = ei[e]; d = ei[EE + e]; }
  else        { s = e - EE; d = s; }
}

__global__ __launch_bounds__(256) void emax_k(const int* __restrict__ ei,
                                              const float* __restrict__ al_s,
                                              const float* __restrict__ al_d,
                                              unsigned* __restrict__ m_u) {
  int t = blockIdx.x * 256 + threadIdx.x;
  if (t >= ETOT * HH) return;
  int e = t >> 2, hh = t & 3;
  int s, d; edge_sd(ei, e, s, d);
  float v = al_s[s * 4 + hh] + al_d[d * 4 + hh];
  v = v > 0.f ? v : 0.2f * v;
  atomicMax(&m_u[d * 4 + hh], enc_f(v));
}

__global__ __launch_bounds__(256) void esum_k(const int* __restrict__ ei,
                                              const float* __restrict__ al_s,
                                              const float* __restrict__ al_d,
                                              const unsigned* __restrict__ m_u,
                                              float* __restrict__ denom) {
  int t = blockIdx.x * 256 + threadIdx.x;
  if (t >= ETOT * HH) return;
  int e = t >> 2, hh = t & 3;
  int s, d; edge_sd(ei, e, s, d);
  float v = al_s[s * 4 + hh] + al_d[d * 4 + hh];
  v = v > 0.f ? v : 0.2f * v;
  float m = dec_f(m_u[d * 4 + hh]);
  atomicAdd(&denom[d * 4 + hh], __expf(v - m));
}

__global__ __launch_bounds__(256) void eagg_k(const int* __restrict__ ei,
                                              const float* __restrict__ al_s,
                                              const float* __restrict__ al_d,
                                              const unsigned* __restrict__ m_u,
                                              const float* __restrict__ denom,
                                              const float* __restrict__ Hh,
                                              float* __restrict__ agg) {
  int t = blockIdx.x * 256 + threadIdx.x;
  if (t >= (int)((long long)ETOT * DD)) return;
  int e = t >> 7, f = t & 127, hh = f >> 5;
  int s, d; edge_sd(ei, e, s, d);
  float v = al_s[s * 4 + hh] + al_d[d * 4 + hh];
  v = v > 0.f ? v : 0.2f * v;
  float m = dec_f(m_u[d * 4 + hh]);
  float alpha = __fdividef(__expf(v - m), denom[d * 4 + hh]);
  atomicAdd(&agg[(size_t)d * DD + f], Hh[(size_t)s * DD + f] * alpha);
}

// in-place: x += bias; LayerNorm; LeakyReLU(0.1). One wave per node.
__global__ __launch_bounds__(256) void ln_k(float* __restrict__ io,
                                            const float* __restrict__ bias,
                                            const float* __restrict__ gamma,
                                            const float* __restrict__ beta) {
  int wave = threadIdx.x >> 6, lane = threadIdx.x & 63;
  int n = blockIdx.x * 4 + wave;
  if (n >= NN) return;
  float x0 = io[(size_t)n * DD + lane] + bias[lane];
  float x1 = io[(size_t)n * DD + 64 + lane] + bias[64 + lane];
  float sum = x0 + x1, ssq = x0 * x0 + x1 * x1;
#pragma unroll
  for (int off = 32; off; off >>= 1) {
    sum += __shfl_xor(sum, off);
    ssq += __shfl_xor(ssq, off);
  }
  float mu = sum * (1.f / 128.f);
  float var = ssq * (1.f / 128.f) - mu * mu;
  float rstd = rsqrtf(var + 1e-5f);
  float y0 = (x0 - mu) * rstd * gamma[lane] + beta[lane];
  float y1 = (x1 - mu) * rstd * gamma[64 + lane] + beta[64 + lane];
  y0 = y0 > 0.f ? y0 : 0.1f * y0;
  y1 = y1 > 0.f ? y1 : 0.1f * y1;
  io[(size_t)n * DD + lane] = y0;
  io[(size_t)n * DD + 64 + lane] = y1;
}

__global__ __launch_bounds__(256) void pool_k(const float* __restrict__ xin,
                                              const int* __restrict__ batch,
                                              unsigned* __restrict__ gmax_u,
                                              float* __restrict__ gsum,
                                              float* __restrict__ cnt) {
  int t = blockIdx.x * 256 + threadIdx.x;
  if (t >= NN * DD) return;
  int n = t >> 7, f = t & 127;
  int g = batch[n];
  float v = xin[(size_t)n * DD + f];
  atomicMax(&gmax_u[g * DD + f], enc_f(v));
  atomicAdd(&gsum[g * DD + f], v);
  if (f == 0) atomicAdd(&cnt[g], 1.f);
}

__global__ __launch_bounds__(128) void final_k(const unsigned* __restrict__ gmax_u,
                                               const float* __restrict__ gsum,
                                               const float* __restrict__ cnt,
                                               const float* __restrict__ Wout,
                                               const float* __restrict__ bout,
                                               float* __restrict__ out) {
  __shared__ float sp[256];
  int g = blockIdx.x, t = threadIdx.x;
  sp[t] = dec_f(gmax_u[g * DD + t]);
  float c = cnt[g];
  c = c > 1.f ? c : 1.f;
  sp[128 + t] = gsum[g * DD + t] / c;
  __syncthreads();
  float acc = bout[t];
  for (int k = 0; k < 256; ++k) acc += sp[k] * Wout[k * 128 + t];
  out[(size_t)g * 128 + t] = acc;
}

extern "C" void kernel_launch(void* const* d_in, const int* in_sizes, int n_in,
                              void* d_out, int out_size, void* d_ws, size_t ws_size,
                              hipStream_t stream) {
  const float* x       = (const float*)d_in[0];
  const int*   ei      = (const int*)d_in[1];
  const int*   batch   = (const int*)d_in[2];
  const float* W       = (const float*)d_in[3];
  const float* att_src = (const float*)d_in[4];
  const float* att_dst = (const float*)d_in[5];
  const float* bias    = (const float*)d_in[6];
  const float* gamma   = (const float*)d_in[7];
  const float* beta    = (const float*)d_in[8];
  const float* Wout    = (const float*)d_in[9];
  const float* bout    = (const float*)d_in[10];
  float* out = (float*)d_out;

  char* ws = (char*)d_ws;
  float*    HB     = (float*)ws;    ws += (size_t)NN * DD * 4;   // h of current layer
  float*    AB     = (float*)ws;    ws += (size_t)NN * DD * 4;   // agg / layer output
  float*    als    = (float*)ws;    ws += (size_t)NN * HH * 4;
  float*    ald    = (float*)ws;    ws += (size_t)NN * HH * 4;
  unsigned* m_u    = (unsigned*)ws; ws += (size_t)NN * HH * 4;
  float*    denom  = (float*)ws;    ws += (size_t)NN * HH * 4;
  unsigned* gmax_u = (unsigned*)ws; ws += (size_t)GG * DD * 4;
  float*    gsum   = (float*)ws;    ws += (size_t)GG * DD * 4;
  float*    cnt    = (float*)ws;    ws += (size_t)GG * 4;

  const int EB = (ETOT * HH + 255) / 256;
  const int FB = (int)(((long long)ETOT * DD + 255) / 256);

  const float* in = x;
  for (int l = 0; l < LL; ++l) {
    gemm_k<<<(NN + 31) / 32, 256, 0, stream>>>(in, W + (size_t)l * DD * DD, HB);
    al_k<<<(NN + 3) / 4, 256, 0, stream>>>(HB, att_src + l * DD, att_dst + l * DD, als, ald);
    // GEMM has consumed `in` (== AB for l>0); safe to reuse AB as the agg buffer.
    hipMemsetAsync(AB, 0, (size_t)NN * DD * 4, stream);
    hipMemsetAsync(m_u, 0, (size_t)NN * HH * 4, stream);   // enc-uint 0 == -max float
    hipMemsetAsync(denom, 0, (size_t)NN * HH * 4, stream);
    emax_k<<<EB, 256, 0, stream>>>(ei, als, ald, m_u);
    esum_k<<<EB, 256, 0, stream>>>(ei, als, ald, m_u, denom);
    eagg_k<<<FB, 256, 0, stream>>>(ei, als, ald, m_u, denom, HB, AB);
    ln_k<<<(NN + 3) / 4, 256, 0, stream>>>(AB, bias + l * DD, gamma + l * DD, beta + l * DD);
    in = AB;
  }

  hipMemsetAsync(gmax_u, 0, (size_t)GG * DD * 4, stream);
  hipMemsetAsync(gsum, 0, (size_t)GG * DD * 4, stream);
  hipMemsetAsync(cnt, 0, (size_t)GG * 4, stream);
  pool_k<<<(NN * DD + 255) / 256, 256, 0, stream>>>(AB, batch, gmax_u, gsum, cnt);
  final_k<<<GG, 128, 0, stream>>>(gmax_u, gsum, cnt, Wout, bout, out);
}

// Round 2
// 838.392 us; speedup vs baseline: 2.1212x; 2.1212x over previous
//
#include <hip/hip_runtime.h>

#define NN 50000
#define EE 800000
#define ETOT (EE + NN)
#define GG 256
#define LL 3
#define HH 4
#define DD 128

#define NEG_SENT (-1e30f)

// Monotone float<->uint mapping so unsigned atomicMax == float max.
__device__ __forceinline__ unsigned enc_f(float f) {
  unsigned b = __float_as_uint(f);
  return (b & 0x80000000u) ? ~b : (b | 0x80000000u);
}
__device__ __forceinline__ float dec_f(unsigned u) {
  unsigned b = (u & 0x80000000u) ? (u & 0x7FFFFFFFu) : ~u;
  return __uint_as_float(b);
}

// h = A[N,128] @ W[128,128]; 32-row tile per block, full W staged in LDS.
__global__ __launch_bounds__(256) void gemm_k(const float* __restrict__ A,
                                              const float* __restrict__ Wl,
                                              float* __restrict__ Hh) {
  __shared__ float sW[128 * 128];   // 64 KB
  __shared__ float sA[32][128];     // 16 KB
  int tid = threadIdx.x;
  for (int i = tid; i < 128 * 128; i += 256) sW[i] = Wl[i];
  int row0 = blockIdx.x * 32;
  for (int i = tid; i < 32 * 128; i += 256) {
    int r = i >> 7, c = i & 127;
    int gr = row0 + r;
    sA[r][c] = (gr < NN) ? A[(size_t)gr * DD + c] : 0.f;
  }
  __syncthreads();
  int tc = tid & 31;
  int tr = tid >> 5;
  float acc[4][4] = {};
  for (int k = 0; k < 128; ++k) {
    float4 w = *(const float4*)&sW[k * 128 + tc * 4];
    float a[4];
#pragma unroll
    for (int r = 0; r < 4; ++r) a[r] = sA[tr * 4 + r][k];
#pragma unroll
    for (int r = 0; r < 4; ++r) {
      acc[r][0] += a[r] * w.x;
      acc[r][1] += a[r] * w.y;
      acc[r][2] += a[r] * w.z;
      acc[r][3] += a[r] * w.w;
    }
  }
#pragma unroll
  for (int r = 0; r < 4; ++r) {
    int gr = row0 + tr * 4 + r;
    if (gr < NN) {
      float4 o = {acc[r][0], acc[r][1], acc[r][2], acc[r][3]};
      *(float4*)&Hh[(size_t)gr * DD + tc * 4] = o;
    }
  }
}

// Per-node attention logits al_s[n][h], al_d[n][h]; one wave per node.
__global__ __launch_bounds__(256) void al_k(const float* __restrict__ Hh,
                                            const float* __restrict__ asrc,
                                            const float* __restrict__ adst,
                                            float* __restrict__ al_s,
                                            float* __restrict__ al_d) {
  int wave = threadIdx.x >> 6;
  int lane = threadIdx.x & 63;
  int n = blockIdx.x * 4 + wave;
  if (n >= NN) return;
  int f0 = lane, f1 = lane + 64;
  float h0 = Hh[(size_t)n * DD + f0], h1 = Hh[(size_t)n * DD + f1];
  float s0 = h0 * asrc[f0], s1 = h1 * asrc[f1];
  float d0 = h0 * adst[f0], d1 = h1 * adst[f1];
#pragma unroll
  for (int off = 16; off; off >>= 1) {
    s0 += __shfl_xor(s0, off);
    s1 += __shfl_xor(s1, off);
    d0 += __shfl_xor(d0, off);
    d1 += __shfl_xor(d1, off);
  }
  if ((lane & 31) == 0) {
    int hg = lane >> 5;
    al_s[n * 4 + hg] = s0;
    al_s[n * 4 + 2 + hg] = s1;
    al_d[n * 4 + hg] = d0;
    al_d[n * 4 + 2 + hg] = d1;
  }
}

// ---- CSR build (once per launch; reused by all 3 layers) ----
__global__ __launch_bounds__(256) void deg_k(const int* __restrict__ ei,
                                             int* __restrict__ deg) {
  int e = blockIdx.x * 256 + threadIdx.x;
  if (e >= ETOT) return;
  int d = (e < EE) ? ei[EE + e] : (e - EE);
  atomicAdd(&deg[d], 1);
}

__global__ __launch_bounds__(1024) void scan_k(const int* __restrict__ deg,
                                               int* __restrict__ rp) {
  __shared__ int sb[1024];
  int t = threadIdx.x;
  const int CH = (NN + 1023) / 1024;  // 49
  int base = t * CH;
  int sum = 0;
  for (int i = 0; i < CH; ++i) {
    int idx = base + i;
    if (idx < NN) sum += deg[idx];
  }
  sb[t] = sum;
  __syncthreads();
  for (int off = 1; off < 1024; off <<= 1) {
    int v = (t >= off) ? sb[t - off] : 0;
    __syncthreads();
    sb[t] += v;
    __syncthreads();
  }
  int run = sb[t] - sum;  // exclusive prefix of this thread's chunk
  for (int i = 0; i < CH; ++i) {
    int idx = base + i;
    if (idx < NN) { rp[idx] = run; run += deg[idx]; }
  }
  if (t == 1023) rp[NN] = ETOT;
}

__global__ __launch_bounds__(256) void scatter_k(const int* __restrict__ ei,
                                                 int* __restrict__ cur,
                                                 int* __restrict__ col) {
  int e = blockIdx.x * 256 + threadIdx.x;
  if (e >= ETOT) return;
  int s, d;
  if (e < EE) { s = ei[e]; d = ei[EE + e]; }
  else        { s = e - EE; d = s; }
  int pos = atomicAdd(&cur[d], 1);
  col[pos] = s;
}

// ---- Fused per-node: segment-softmax + weighted agg + bias + LN + LeakyReLU ----
// One wave per dst node. No atomics.
__global__ __launch_bounds__(256) void agg_k(const int* __restrict__ rp,
                                             const int* __restrict__ col,
                                             const float* __restrict__ als,
                                             const float* __restrict__ ald,
                                             const float* __restrict__ Hh,
                                             const float* __restrict__ bias,
                                             const float* __restrict__ gamma,
                                             const float* __restrict__ beta,
                                             float* __restrict__ outb) {
  int wave = threadIdx.x >> 6, lane = threadIdx.x & 63;
  int n = blockIdx.x * 4 + wave;
  if (n >= NN) return;
  int e0 = rp[n], e1 = rp[n + 1];
  float4 ad = *(const float4*)&ald[(size_t)n * 4];

  // Pass A: per-lane online softmax stats per head over strided edges.
  float m[4] = {NEG_SENT, NEG_SENT, NEG_SENT, NEG_SENT};
  float s[4] = {0.f, 0.f, 0.f, 0.f};
  for (int e = e0 + lane; e < e1; e += 64) {
    int sn = col[e];
    float4 as = *(const float4*)&als[(size_t)sn * 4];
    float v[4] = {as.x + ad.x, as.y + ad.y, as.z + ad.z, as.w + ad.w};
#pragma unroll
    for (int h = 0; h < 4; ++h) {
      float vv = v[h] > 0.f ? v[h] : 0.2f * v[h];
      if (vv > m[h]) {
        s[h] = s[h] * __expf(m[h] - vv) + 1.f;
        m[h] = vv;
      } else {
        s[h] += __expf(vv - m[h]);
      }
    }
  }
  // Wave merge of (m, s) pairs.
#pragma unroll
  for (int off = 32; off; off >>= 1) {
#pragma unroll
    for (int h = 0; h < 4; ++h) {
      float mo = __shfl_xor(m[h], off);
      float so = __shfl_xor(s[h], off);
      float M = fmaxf(m[h], mo);
      s[h] = s[h] * __expf(m[h] - M) + so * __expf(mo - M);
      m[h] = M;
    }
  }

  // Pass B: sequential edge loop; each lane owns features 2*lane, 2*lane+1.
  int hh = lane >> 4;  // head of this lane's features
  float mh = m[hh];
  float rdh = __fdividef(1.f, s[hh]);
  float adh = (hh == 0) ? ad.x : (hh == 1) ? ad.y : (hh == 2) ? ad.z : ad.w;
  float a0 = 0.f, a1 = 0.f;
  int e = e0;
  while (e < e1) {
    int cnt = min(64, e1 - e);
    int myS = (lane < cnt) ? col[e + lane] : 0;
    for (int j = 0; j < cnt; ++j) {
      int sn = __shfl(myS, j);
      float v = als[(size_t)sn * 4 + hh] + adh;
      v = v > 0.f ? v : 0.2f * v;
      float alpha = __expf(v - mh) * rdh;
      float2 hv = *(const float2*)&Hh[(size_t)sn * DD + 2 * lane];
      a0 = __fmaf_rn(alpha, hv.x, a0);
      a1 = __fmaf_rn(alpha, hv.y, a1);
    }
    e += cnt;
  }

  // bias + LayerNorm + LeakyReLU(0.1), in-register.
  int f0 = 2 * lane, f1 = 2 * lane + 1;
  float x0 = a0 + bias[f0], x1 = a1 + bias[f1];
  float sum = x0 + x1, ssq = x0 * x0 + x1 * x1;
#pragma unroll
  for (int off = 32; off; off >>= 1) {
    sum += __shfl_xor(sum, off);
    ssq += __shfl_xor(ssq, off);
  }
  float mu = sum * (1.f / 128.f);
  float var = ssq * (1.f / 128.f) - mu * mu;
  float rstd = rsqrtf(var + 1e-5f);
  float y0 = (x0 - mu) * rstd * gamma[f0] + beta[f0];
  float y1 = (x1 - mu) * rstd * gamma[f1] + beta[f1];
  y0 = y0 > 0.f ? y0 : 0.1f * y0;
  y1 = y1 > 0.f ? y1 : 0.1f * y1;
  float2 o = {y0, y1};
  *(float2*)&outb[(size_t)n * DD + f0] = o;
}

__global__ __launch_bounds__(256) void pool_k(const float* __restrict__ xin,
                                              const int* __restrict__ batch,
                                              unsigned* __restrict__ gmax_u,
                                              float* __restrict__ gsum,
                                              float* __restrict__ cnt) {
  int t = blockIdx.x * 256 + threadIdx.x;
  if (t >= NN * DD) return;
  int n = t >> 7, f = t & 127;
  int g = batch[n];
  float v = xin[(size_t)n * DD + f];
  atomicMax(&gmax_u[g * DD + f], enc_f(v));
  atomicAdd(&gsum[g * DD + f], v);
  if (f == 0) atomicAdd(&cnt[g], 1.f);
}

__global__ __launch_bounds__(128) void final_k(const unsigned* __restrict__ gmax_u,
                                               const float* __restrict__ gsum,
                                               const float* __restrict__ cnt,
                                               const float* __restrict__ Wout,
                                               const float* __restrict__ bout,
                                               float* __restrict__ out) {
  __shared__ float sp[256];
  int g = blockIdx.x, t = threadIdx.x;
  sp[t] = dec_f(gmax_u[g * DD + t]);
  float c = cnt[g];
  c = c > 1.f ? c : 1.f;
  sp[128 + t] = gsum[g * DD + t] / c;
  __syncthreads();
  float acc = bout[t];
  for (int k = 0; k < 256; ++k) acc += sp[k] * Wout[k * 128 + t];
  out[(size_t)g * 128 + t] = acc;
}

extern "C" void kernel_launch(void* const* d_in, const int* in_sizes, int n_in,
                              void* d_out, int out_size, void* d_ws, size_t ws_size,
                              hipStream_t stream) {
  const float* x       = (const float*)d_in[0];
  const int*   ei      = (const int*)d_in[1];
  const int*   batch   = (const int*)d_in[2];
  const float* W       = (const float*)d_in[3];
  const float* att_src = (const float*)d_in[4];
  const float* att_dst = (const float*)d_in[5];
  const float* bias    = (const float*)d_in[6];
  const float* gamma   = (const float*)d_in[7];
  const float* beta    = (const float*)d_in[8];
  const float* Wout    = (const float*)d_in[9];
  const float* bout    = (const float*)d_in[10];
  float* out = (float*)d_out;

  char* ws = (char*)d_ws;
  float*    HB     = (float*)ws;    ws += (size_t)NN * DD * 4;
  float*    AB     = (float*)ws;    ws += (size_t)NN * DD * 4;
  float*    als    = (float*)ws;    ws += (size_t)NN * HH * 4;
  float*    ald    = (float*)ws;    ws += (size_t)NN * HH * 4;
  int*      rp     = (int*)ws;      ws += (size_t)(NN + 1) * 4;
  int*      deg    = (int*)ws;      ws += (size_t)NN * 4;      // reused as scatter cursor
  int*      col    = (int*)ws;      ws += (size_t)ETOT * 4;
  unsigned* gmax_u = (unsigned*)ws; ws += (size_t)GG * DD * 4;
  float*    gsum   = (float*)ws;    ws += (size_t)GG * DD * 4;
  float*    cnt    = (float*)ws;    ws += (size_t)GG * 4;

  const int EB = (ETOT + 255) / 256;

  // ---- CSR build (once) ----
  hipMemsetAsync(deg, 0, (size_t)NN * 4, stream);
  deg_k<<<EB, 256, 0, stream>>>(ei, deg);
  scan_k<<<1, 1024, 0, stream>>>(deg, rp);
  hipMemcpyAsync(deg, rp, (size_t)NN * 4, hipMemcpyDeviceToDevice, stream);  // cursor
  scatter_k<<<EB, 256, 0, stream>>>(ei, deg, col);

  // ---- layers ----
  const float* in = x;
  for (int l = 0; l < LL; ++l) {
    gemm_k<<<(NN + 31) / 32, 256, 0, stream>>>(in, W + (size_t)l * DD * DD, HB);
    al_k<<<(NN + 3) / 4, 256, 0, stream>>>(HB, att_src + l * DD, att_dst + l * DD, als, ald);
    agg_k<<<(NN + 3) / 4, 256, 0, stream>>>(rp, col, als, ald, HB,
                                            bias + l * DD, gamma + l * DD, beta + l * DD, AB);
    in = AB;
  }

  // ---- pooling + output GEMM ----
  hipMemsetAsync(gmax_u, 0, (size_t)GG * DD * 4, stream);
  hipMemsetAsync(gsum, 0, (size_t)GG * DD * 4, stream);
  hipMemsetAsync(cnt, 0, (size_t)GG * 4, stream);
  pool_k<<<(NN * DD + 255) / 256, 256, 0, stream>>>(AB, batch, gmax_u, gsum, cnt);
  final_k<<<GG, 128, 0, stream>>>(gmax_u, gsum, cnt, Wout, bout, out);
}

// Round 3
// 618.245 us; speedup vs baseline: 2.8765x; 1.3561x over previous
//
#include <hip/hip_runtime.h>

#define NN 50000
#define EE 800000
#define ETOT (EE + NN)
#define GG 256
#define LL 3
#define HH 4
#define DD 128

#define NEG_SENT (-1e30f)

// h = A[N,128] @ W[128,128]; 32-row tile per block, full W staged in LDS.
__global__ __launch_bounds__(256) void gemm_k(const float* __restrict__ A,
                                              const float* __restrict__ Wl,
                                              float* __restrict__ Hh) {
  __shared__ float sW[128 * 128];   // 64 KB
  __shared__ float sA[32][128];     // 16 KB
  int tid = threadIdx.x;
  for (int i = tid; i < 128 * 128; i += 256) sW[i] = Wl[i];
  int row0 = blockIdx.x * 32;
  for (int i = tid; i < 32 * 128; i += 256) {
    int r = i >> 7, c = i & 127;
    int gr = row0 + r;
    sA[r][c] = (gr < NN) ? A[(size_t)gr * DD + c] : 0.f;
  }
  __syncthreads();
  int tc = tid & 31;
  int tr = tid >> 5;
  float acc[4][4] = {};
  for (int k = 0; k < 128; ++k) {
    float4 w = *(const float4*)&sW[k * 128 + tc * 4];
    float a[4];
#pragma unroll
    for (int r = 0; r < 4; ++r) a[r] = sA[tr * 4 + r][k];
#pragma unroll
    for (int r = 0; r < 4; ++r) {
      acc[r][0] += a[r] * w.x;
      acc[r][1] += a[r] * w.y;
      acc[r][2] += a[r] * w.z;
      acc[r][3] += a[r] * w.w;
    }
  }
#pragma unroll
  for (int r = 0; r < 4; ++r) {
    int gr = row0 + tr * 4 + r;
    if (gr < NN) {
      float4 o = {acc[r][0], acc[r][1], acc[r][2], acc[r][3]};
      *(float4*)&Hh[(size_t)gr * DD + tc * 4] = o;
    }
  }
}

// Per-node attention logits al_s[n][h], al_d[n][h]; one wave per node.
__global__ __launch_bounds__(256) void al_k(const float* __restrict__ Hh,
                                            const float* __restrict__ asrc,
                                            const float* __restrict__ adst,
                                            float* __restrict__ al_s,
                                            float* __restrict__ al_d) {
  int wave = threadIdx.x >> 6;
  int lane = threadIdx.x & 63;
  int n = blockIdx.x * 4 + wave;
  if (n >= NN) return;
  int f0 = lane, f1 = lane + 64;
  float h0 = Hh[(size_t)n * DD + f0], h1 = Hh[(size_t)n * DD + f1];
  float s0 = h0 * asrc[f0], s1 = h1 * asrc[f1];
  float d0 = h0 * adst[f0], d1 = h1 * adst[f1];
#pragma unroll
  for (int off = 16; off; off >>= 1) {
    s0 += __shfl_xor(s0, off);
    s1 += __shfl_xor(s1, off);
    d0 += __shfl_xor(d0, off);
    d1 += __shfl_xor(d1, off);
  }
  if ((lane & 31) == 0) {
    int hg = lane >> 5;
    al_s[n * 4 + hg] = s0;
    al_s[n * 4 + 2 + hg] = s1;
    al_d[n * 4 + hg] = d0;
    al_d[n * 4 + 2 + hg] = d1;
  }
}

// ---- CSR build (once per launch; reused by all 3 layers) ----
__global__ __launch_bounds__(256) void deg_k(const int* __restrict__ ei,
                                             int* __restrict__ deg) {
  int e = blockIdx.x * 256 + threadIdx.x;
  if (e >= ETOT) return;
  int d = (e < EE) ? ei[EE + e] : (e - EE);
  atomicAdd(&deg[d], 1);
}

// Prefix-scan; writes row pointers AND the scatter cursor (into the deg buffer).
__global__ __launch_bounds__(1024) void scan_k(int* __restrict__ deg,
                                               int* __restrict__ rp) {
  __shared__ int sb[1024];
  int t = threadIdx.x;
  const int CH = (NN + 1023) / 1024;  // 49
  int base = t * CH;
  int sum = 0;
  for (int i = 0; i < CH; ++i) {
    int idx = base + i;
    if (idx < NN) sum += deg[idx];
  }
  sb[t] = sum;
  __syncthreads();
  for (int off = 1; off < 1024; off <<= 1) {
    int v = (t >= off) ? sb[t - off] : 0;
    __syncthreads();
    sb[t] += v;
    __syncthreads();
  }
  int run = sb[t] - sum;  // exclusive prefix of this thread's chunk
  for (int i = 0; i < CH; ++i) {
    int idx = base + i;
    if (idx < NN) {
      int dv = deg[idx];
      rp[idx] = run;
      deg[idx] = run;   // cursor for scatter_k
      run += dv;
    }
  }
  if (t == 1023) rp[NN] = ETOT;
}

__global__ __launch_bounds__(256) void scatter_k(const int* __restrict__ ei,
                                                 int* __restrict__ cur,
                                                 int* __restrict__ col) {
  int e = blockIdx.x * 256 + threadIdx.x;
  if (e >= ETOT) return;
  int s, d;
  if (e < EE) { s = ei[e]; d = ei[EE + e]; }
  else        { s = e - EE; d = s; }
  int pos = atomicAdd(&cur[d], 1);
  col[pos] = s;
}

// Graph start offsets from the SORTED batch array: gs[g] = lower_bound(batch, g).
__global__ __launch_bounds__(64) void gstart_k(const int* __restrict__ batch,
                                               int* __restrict__ gs) {
  int g = blockIdx.x * 64 + threadIdx.x;
  if (g > GG) return;
  int lo = 0, hi = NN;
  while (lo < hi) {
    int mid = (lo + hi) >> 1;
    if (batch[mid] < g) lo = mid + 1; else hi = mid;
  }
  gs[g] = lo;
}

// ---- Fused per-node: segment-softmax + weighted agg + bias + LN + LeakyReLU ----
// One wave per dst node; 4 nodes per block. No atomics. 12500*4 == NN exactly.
__global__ __launch_bounds__(256) void agg_k(const int* __restrict__ rp,
                                             const int* __restrict__ col,
                                             const float* __restrict__ als,
                                             const float* __restrict__ ald,
                                             const float* __restrict__ Hh,
                                             const float* __restrict__ bias,
                                             const float* __restrict__ gamma,
                                             const float* __restrict__ beta,
                                             float* __restrict__ outb) {
  __shared__ float salpha[4][4][65];  // [wave][head][edge], padded stride
  __shared__ int   scol[4][64];
  int wave = threadIdx.x >> 6, lane = threadIdx.x & 63;
  int n = blockIdx.x * 4 + wave;
  if (n >= NN) return;
  int e0 = rp[n], e1 = rp[n + 1];
  int deg = e1 - e0;
  float4 ad = *(const float4*)&ald[(size_t)n * 4];
  int hh = lane >> 4;  // head of this lane's feature pair
  float a0 = 0.f, a1 = 0.f;

  if (deg <= 64) {
    // --- fast path: one edge per lane ---
    int sn = (lane < deg) ? col[e0 + lane] : -1;
    float4 as;
    if (sn >= 0) as = *(const float4*)&als[(size_t)sn * 4];
    else         as = make_float4(0.f, 0.f, 0.f, 0.f);
    float vv[4] = {as.x + ad.x, as.y + ad.y, as.z + ad.z, as.w + ad.w};
#pragma unroll
    for (int h = 0; h < 4; ++h) {
      float t = vv[h];
      t = t > 0.f ? t : 0.2f * t;
      vv[h] = (sn >= 0) ? t : NEG_SENT;
    }
    float m[4] = {vv[0], vv[1], vv[2], vv[3]};
#pragma unroll
    for (int off = 32; off; off >>= 1) {
#pragma unroll
      for (int h = 0; h < 4; ++h) m[h] = fmaxf(m[h], __shfl_xor(m[h], off));
    }
    float p[4], s[4];
#pragma unroll
    for (int h = 0; h < 4; ++h) {
      p[h] = (sn >= 0) ? __expf(vv[h] - m[h]) : 0.f;
      s[h] = p[h];
    }
#pragma unroll
    for (int off = 32; off; off >>= 1) {
#pragma unroll
      for (int h = 0; h < 4; ++h) s[h] += __shfl_xor(s[h], off);
    }
    scol[wave][lane] = sn;
#pragma unroll
    for (int h = 0; h < 4; ++h)
      salpha[wave][h][lane] = __fdividef(p[h], s[h]);
    asm volatile("s_waitcnt lgkmcnt(0)" ::: "memory");
#pragma unroll 4
    for (int j = 0; j < deg; ++j) {
      int snj = scol[wave][j];            // LDS broadcast
      float alpha = salpha[wave][hh][j];  // LDS broadcast per head group
      float2 hv = *(const float2*)&Hh[(size_t)snj * DD + 2 * lane];
      a0 = __fmaf_rn(alpha, hv.x, a0);
      a1 = __fmaf_rn(alpha, hv.y, a1);
    }
  } else {
    // --- fallback: online two-pass (any degree) ---
    float m[4] = {NEG_SENT, NEG_SENT, NEG_SENT, NEG_SENT};
    float s[4] = {0.f, 0.f, 0.f, 0.f};
    for (int e = e0 + lane; e < e1; e += 64) {
      int sn = col[e];
      float4 as = *(const float4*)&als[(size_t)sn * 4];
      float v[4] = {as.x + ad.x, as.y + ad.y, as.z + ad.z, as.w + ad.w};
#pragma unroll
      for (int h = 0; h < 4; ++h) {
        float vvv = v[h] > 0.f ? v[h] : 0.2f * v[h];
        if (vvv > m[h]) { s[h] = s[h] * __expf(m[h] - vvv) + 1.f; m[h] = vvv; }
        else             s[h] += __expf(vvv - m[h]);
      }
    }
#pragma unroll
    for (int off = 32; off; off >>= 1) {
#pragma unroll
      for (int h = 0; h < 4; ++h) {
        float mo = __shfl_xor(m[h], off);
        float so = __shfl_xor(s[h], off);
        float M = fmaxf(m[h], mo);
        s[h] = s[h] * __expf(m[h] - M) + so * __expf(mo - M);
        m[h] = M;
      }
    }
    float mh = m[hh];
    float rdh = __fdividef(1.f, s[hh]);
    float adh = (hh == 0) ? ad.x : (hh == 1) ? ad.y : (hh == 2) ? ad.z : ad.w;
    int e = e0;
    while (e < e1) {
      int cnt = min(64, e1 - e);
      int myS = (lane < cnt) ? col[e + lane] : 0;
      for (int j = 0; j < cnt; ++j) {
        int sn = __shfl(myS, j);
        float v = als[(size_t)sn * 4 + hh] + adh;
        v = v > 0.f ? v : 0.2f * v;
        float alpha = __expf(v - mh) * rdh;
        float2 hv = *(const float2*)&Hh[(size_t)sn * DD + 2 * lane];
        a0 = __fmaf_rn(alpha, hv.x, a0);
        a1 = __fmaf_rn(alpha, hv.y, a1);
      }
      e += cnt;
    }
  }

  // bias + LayerNorm + LeakyReLU(0.1), in-register.
  int f0 = 2 * lane, f1 = 2 * lane + 1;
  float x0 = a0 + bias[f0], x1 = a1 + bias[f1];
  float sum = x0 + x1, ssq = x0 * x0 + x1 * x1;
#pragma unroll
  for (int off = 32; off; off >>= 1) {
    sum += __shfl_xor(sum, off);
    ssq += __shfl_xor(ssq, off);
  }
  float mu = sum * (1.f / 128.f);
  float var = ssq * (1.f / 128.f) - mu * mu;
  float rstd = rsqrtf(var + 1e-5f);
  float y0 = (x0 - mu) * rstd * gamma[f0] + beta[f0];
  float y1 = (x1 - mu) * rstd * gamma[f1] + beta[f1];
  y0 = y0 > 0.f ? y0 : 0.1f * y0;
  y1 = y1 > 0.f ? y1 : 0.1f * y1;
  float2 o = {y0, y1};
  *(float2*)&outb[(size_t)n * DD + f0] = o;
}

// ---- Fused pooling (max+mean over contiguous sorted segments) + output GEMM ----
// One block per graph; thread t owns feature t. No atomics, no memsets.
__global__ __launch_bounds__(128) void poolout_k(const float* __restrict__ xin,
                                                 const int* __restrict__ gs,
                                                 const float* __restrict__ Wout,
                                                 const float* __restrict__ bout,
                                                 float* __restrict__ out) {
  __shared__ float sp[256];
  int g = blockIdx.x, t = threadIdx.x;
  int n0 = gs[g], n1 = gs[g + 1];
  float mx = NEG_SENT, sm = 0.f;
#pragma unroll 4
  for (int n = n0; n < n1; ++n) {
    float v = xin[(size_t)n * DD + t];
    mx = fmaxf(mx, v);
    sm += v;
  }
  float c = (float)(n1 - n0);
  sp[t] = mx;
  sp[128 + t] = sm / fmaxf(c, 1.f);
  __syncthreads();
  float acc = bout[t];
#pragma unroll 8
  for (int k = 0; k < 256; ++k) acc = __fmaf_rn(sp[k], Wout[k * 128 + t], acc);
  out[(size_t)g * 128 + t] = acc;
}

extern "C" void kernel_launch(void* const* d_in, const int* in_sizes, int n_in,
                              void* d_out, int out_size, void* d_ws, size_t ws_size,
                              hipStream_t stream) {
  const float* x       = (const float*)d_in[0];
  const int*   ei      = (const int*)d_in[1];
  const int*   batch   = (const int*)d_in[2];
  const float* W       = (const float*)d_in[3];
  const float* att_src = (const float*)d_in[4];
  const float* att_dst = (const float*)d_in[5];
  const float* bias    = (const float*)d_in[6];
  const float* gamma   = (const float*)d_in[7];
  const float* beta    = (const float*)d_in[8];
  const float* Wout    = (const float*)d_in[9];
  const float* bout    = (const float*)d_in[10];
  float* out = (float*)d_out;

  char* ws = (char*)d_ws;
  float* HB  = (float*)ws; ws += (size_t)NN * DD * 4;
  float* AB  = (float*)ws; ws += (size_t)NN * DD * 4;
  float* als = (float*)ws; ws += (size_t)NN * HH * 4;
  float* ald = (float*)ws; ws += (size_t)NN * HH * 4;
  int*   rp  = (int*)ws;   ws += (size_t)(NN + 1) * 4;
  int*   deg = (int*)ws;   ws += (size_t)NN * 4;      // reused as scatter cursor
  int*   col = (int*)ws;   ws += (size_t)ETOT * 4;
  int*   gs  = (int*)ws;   ws += (size_t)(GG + 1) * 4;

  const int EB = (ETOT + 255) / 256;

  // ---- CSR build + graph offsets (once) ----
  hipMemsetAsync(deg, 0, (size_t)NN * 4, stream);
  deg_k<<<EB, 256, 0, stream>>>(ei, deg);
  scan_k<<<1, 1024, 0, stream>>>(deg, rp);
  scatter_k<<<EB, 256, 0, stream>>>(ei, deg, col);
  gstart_k<<<(GG + 1 + 63) / 64, 64, 0, stream>>>(batch, gs);

  // ---- layers ----
  const float* in = x;
  for (int l = 0; l < LL; ++l) {
    gemm_k<<<(NN + 31) / 32, 256, 0, stream>>>(in, W + (size_t)l * DD * DD, HB);
    al_k<<<(NN + 3) / 4, 256, 0, stream>>>(HB, att_src + l * DD, att_dst + l * DD, als, ald);
    agg_k<<<(NN + 3) / 4, 256, 0, stream>>>(rp, col, als, ald, HB,
                                            bias + l * DD, gamma + l * DD, beta + l * DD, AB);
    in = AB;
  }

  // ---- fused pooling + output GEMM ----
  poolout_k<<<GG, 128, 0, stream>>>(AB, gs, Wout, bout, out);
}

// Round 4
// 504.472 us; speedup vs baseline: 3.5253x; 1.2255x over previous
//
#include <hip/hip_runtime.h>

#define NN 50000
#define EE 800000
#define ETOT (EE + NN)
#define GG 256
#define LL 3
#define HH 4
#define DD 128
#define NBLK ((NN + 255) / 256)   // 196

#define NEG_SENT (-1e30f)

// h = A[N,128] @ W[128,128]; 32-row tile per block, full W staged in LDS.
__global__ __launch_bounds__(256) void gemm_k(const float* __restrict__ A,
                                              const float* __restrict__ Wl,
                                              float* __restrict__ Hh) {
  __shared__ float sW[128 * 128];   // 64 KB
  __shared__ float sA[32][128];     // 16 KB
  int tid = threadIdx.x;
  for (int i = tid; i < 128 * 128; i += 256) sW[i] = Wl[i];
  int row0 = blockIdx.x * 32;
  for (int i = tid; i < 32 * 128; i += 256) {
    int r = i >> 7, c = i & 127;
    int gr = row0 + r;
    sA[r][c] = (gr < NN) ? A[(size_t)gr * DD + c] : 0.f;
  }
  __syncthreads();
  int tc = tid & 31;
  int tr = tid >> 5;
  float acc[4][4] = {};
  for (int k = 0; k < 128; ++k) {
    float4 w = *(const float4*)&sW[k * 128 + tc * 4];
    float a[4];
#pragma unroll
    for (int r = 0; r < 4; ++r) a[r] = sA[tr * 4 + r][k];
#pragma unroll
    for (int r = 0; r < 4; ++r) {
      acc[r][0] += a[r] * w.x;
      acc[r][1] += a[r] * w.y;
      acc[r][2] += a[r] * w.z;
      acc[r][3] += a[r] * w.w;
    }
  }
#pragma unroll
  for (int r = 0; r < 4; ++r) {
    int gr = row0 + tr * 4 + r;
    if (gr < NN) {
      float4 o = {acc[r][0], acc[r][1], acc[r][2], acc[r][3]};
      *(float4*)&Hh[(size_t)gr * DD + tc * 4] = o;
    }
  }
}

// Per-node attention logits al_s[n][h], al_d[n][h]; one wave per node.
__global__ __launch_bounds__(256) void al_k(const float* __restrict__ Hh,
                                            const float* __restrict__ asrc,
                                            const float* __restrict__ adst,
                                            float* __restrict__ al_s,
                                            float* __restrict__ al_d) {
  int wave = threadIdx.x >> 6;
  int lane = threadIdx.x & 63;
  int n = blockIdx.x * 4 + wave;
  if (n >= NN) return;
  int f0 = lane, f1 = lane + 64;
  float h0 = Hh[(size_t)n * DD + f0], h1 = Hh[(size_t)n * DD + f1];
  float s0 = h0 * asrc[f0], s1 = h1 * asrc[f1];
  float d0 = h0 * adst[f0], d1 = h1 * adst[f1];
#pragma unroll
  for (int off = 16; off; off >>= 1) {
    s0 += __shfl_xor(s0, off);
    s1 += __shfl_xor(s1, off);
    d0 += __shfl_xor(d0, off);
    d1 += __shfl_xor(d1, off);
  }
  if ((lane & 31) == 0) {
    int hg = lane >> 5;
    al_s[n * 4 + hg] = s0;
    al_s[n * 4 + 2 + hg] = s1;
    al_d[n * 4 + hg] = d0;
    al_d[n * 4 + 2 + hg] = d1;
  }
}

// ---- CSR build (once per launch; reused by all 3 layers) ----
__global__ __launch_bounds__(256) void deg_k(const int* __restrict__ ei,
                                             int* __restrict__ deg) {
  int e = blockIdx.x * 256 + threadIdx.x;
  if (e >= ETOT) return;
  int d = (e < EE) ? ei[EE + e] : (e - EE);
  atomicAdd(&deg[d], 1);
}

// Device-wide exclusive scan, 3 phases, all parallel.
__global__ __launch_bounds__(256) void scanA_k(const int* __restrict__ deg,
                                               int* __restrict__ rp,
                                               int* __restrict__ bsum) {
  __shared__ int sb[256];
  int t = threadIdx.x, b = blockIdx.x, i = b * 256 + t;
  int d = (i < NN) ? deg[i] : 0;
  sb[t] = d;
  __syncthreads();
#pragma unroll
  for (int off = 1; off < 256; off <<= 1) {
    int v = (t >= off) ? sb[t - off] : 0;
    __syncthreads();
    sb[t] += v;
    __syncthreads();
  }
  if (i < NN) rp[i] = sb[t] - d;       // local exclusive prefix
  if (t == 255) bsum[b] = sb[255];
}

__global__ __launch_bounds__(256) void scanB_k(const int* __restrict__ bsum,
                                               int* __restrict__ boff) {
  __shared__ int sb[256];
  int t = threadIdx.x;
  int d = (t < NBLK) ? bsum[t] : 0;
  sb[t] = d;
  __syncthreads();
#pragma unroll
  for (int off = 1; off < 256; off <<= 1) {
    int v = (t >= off) ? sb[t - off] : 0;
    __syncthreads();
    sb[t] += v;
    __syncthreads();
  }
  if (t < NBLK) boff[t] = sb[t] - d;   // exclusive block offsets
}

__global__ __launch_bounds__(256) void scanC_k(int* __restrict__ rp,
                                               const int* __restrict__ boff,
                                               int* __restrict__ cur) {
  int b = blockIdx.x, i = b * 256 + threadIdx.x;
  if (i < NN) {
    int v = rp[i] + boff[b];
    rp[i] = v;
    cur[i] = v;                        // scatter cursor
  }
  if (i == 0) rp[NN] = ETOT;
}

__global__ __launch_bounds__(256) void scatter_k(const int* __restrict__ ei,
                                                 int* __restrict__ cur,
                                                 int* __restrict__ col) {
  int e = blockIdx.x * 256 + threadIdx.x;
  if (e >= ETOT) return;
  int s, d;
  if (e < EE) { s = ei[e]; d = ei[EE + e]; }
  else        { s = e - EE; d = s; }
  int pos = atomicAdd(&cur[d], 1);
  col[pos] = s;
}

// Graph start offsets from the SORTED batch array: gs[g] = lower_bound(batch, g).
__global__ __launch_bounds__(64) void gstart_k(const int* __restrict__ batch,
                                               int* __restrict__ gs) {
  int g = blockIdx.x * 64 + threadIdx.x;
  if (g > GG) return;
  int lo = 0, hi = NN;
  while (lo < hi) {
    int mid = (lo + hi) >> 1;
    if (batch[mid] < g) lo = mid + 1; else hi = mid;
  }
  gs[g] = lo;
}

// ---- Fused per-node: segment-softmax + weighted agg + bias + LN + LeakyReLU ----
// One wave per dst node; 4 nodes per block. No atomics.
__global__ __launch_bounds__(256) void agg_k(const int* __restrict__ rp,
                                             const int* __restrict__ col,
                                             const float* __restrict__ als,
                                             const float* __restrict__ ald,
                                             const float* __restrict__ Hh,
                                             const float* __restrict__ bias,
                                             const float* __restrict__ gamma,
                                             const float* __restrict__ beta,
                                             float* __restrict__ outb) {
  __shared__ float salpha[4][4][65];  // [wave][head][edge], padded stride
  __shared__ int   scol[4][64];
  int wave = threadIdx.x >> 6, lane = threadIdx.x & 63;
  int n = blockIdx.x * 4 + wave;
  if (n >= NN) return;
  int e0 = rp[n], e1 = rp[n + 1];
  int deg = e1 - e0;
  float4 ad = *(const float4*)&ald[(size_t)n * 4];
  int hh = lane >> 4;  // head of this lane's feature pair
  float a0 = 0.f, a1 = 0.f;

  if (deg <= 64) {
    // --- fast path: one edge per lane ---
    int sn = (lane < deg) ? col[e0 + lane] : -1;
    float4 as;
    if (sn >= 0) as = *(const float4*)&als[(size_t)sn * 4];
    else         as = make_float4(0.f, 0.f, 0.f, 0.f);
    float vv[4] = {as.x + ad.x, as.y + ad.y, as.z + ad.z, as.w + ad.w};
#pragma unroll
    for (int h = 0; h < 4; ++h) {
      float t = vv[h];
      t = t > 0.f ? t : 0.2f * t;
      vv[h] = (sn >= 0) ? t : NEG_SENT;
    }
    float m[4] = {vv[0], vv[1], vv[2], vv[3]};
#pragma unroll
    for (int off = 32; off; off >>= 1) {
#pragma unroll
      for (int h = 0; h < 4; ++h) m[h] = fmaxf(m[h], __shfl_xor(m[h], off));
    }
    float p[4], s[4];
#pragma unroll
    for (int h = 0; h < 4; ++h) {
      p[h] = (sn >= 0) ? __expf(vv[h] - m[h]) : 0.f;
      s[h] = p[h];
    }
#pragma unroll
    for (int off = 32; off; off >>= 1) {
#pragma unroll
      for (int h = 0; h < 4; ++h) s[h] += __shfl_xor(s[h], off);
    }
    scol[wave][lane] = sn;
#pragma unroll
    for (int h = 0; h < 4; ++h)
      salpha[wave][h][lane] = __fdividef(p[h], s[h]);
    asm volatile("s_waitcnt lgkmcnt(0)" ::: "memory");
#pragma unroll 4
    for (int j = 0; j < deg; ++j) {
      int snj = scol[wave][j];            // LDS broadcast
      float alpha = salpha[wave][hh][j];  // LDS broadcast per head group
      float2 hv = *(const float2*)&Hh[(size_t)snj * DD + 2 * lane];
      a0 = __fmaf_rn(alpha, hv.x, a0);
      a1 = __fmaf_rn(alpha, hv.y, a1);
    }
  } else {
    // --- fallback: online two-pass (any degree) ---
    float m[4] = {NEG_SENT, NEG_SENT, NEG_SENT, NEG_SENT};
    float s[4] = {0.f, 0.f, 0.f, 0.f};
    for (int e = e0 + lane; e < e1; e += 64) {
      int sn = col[e];
      float4 as = *(const float4*)&als[(size_t)sn * 4];
      float v[4] = {as.x + ad.x, as.y + ad.y, as.z + ad.z, as.w + ad.w};
#pragma unroll
      for (int h = 0; h < 4; ++h) {
        float vvv = v[h] > 0.f ? v[h] : 0.2f * v[h];
        if (vvv > m[h]) { s[h] = s[h] * __expf(m[h] - vvv) + 1.f; m[h] = vvv; }
        else             s[h] += __expf(vvv - m[h]);
      }
    }
#pragma unroll
    for (int off = 32; off; off >>= 1) {
#pragma unroll
      for (int h = 0; h < 4; ++h) {
        float mo = __shfl_xor(m[h], off);
        float so = __shfl_xor(s[h], off);
        float M = fmaxf(m[h], mo);
        s[h] = s[h] * __expf(m[h] - M) + so * __expf(mo - M);
        m[h] = M;
      }
    }
    float mh = m[hh];
    float rdh = __fdividef(1.f, s[hh]);
    float adh = (hh == 0) ? ad.x : (hh == 1) ? ad.y : (hh == 2) ? ad.z : ad.w;
    int e = e0;
    while (e < e1) {
      int cnt = min(64, e1 - e);
      int myS = (lane < cnt) ? col[e + lane] : 0;
      for (int j = 0; j < cnt; ++j) {
        int sn = __shfl(myS, j);
        float v = als[(size_t)sn * 4 + hh] + adh;
        v = v > 0.f ? v : 0.2f * v;
        float alpha = __expf(v - mh) * rdh;
        float2 hv = *(const float2*)&Hh[(size_t)sn * DD + 2 * lane];
        a0 = __fmaf_rn(alpha, hv.x, a0);
        a1 = __fmaf_rn(alpha, hv.y, a1);
      }
      e += cnt;
    }
  }

  // bias + LayerNorm + LeakyReLU(0.1), in-register.
  int f0 = 2 * lane, f1 = 2 * lane + 1;
  float x0 = a0 + bias[f0], x1 = a1 + bias[f1];
  float sum = x0 + x1, ssq = x0 * x0 + x1 * x1;
#pragma unroll
  for (int off = 32; off; off >>= 1) {
    sum += __shfl_xor(sum, off);
    ssq += __shfl_xor(ssq, off);
  }
  float mu = sum * (1.f / 128.f);
  float var = ssq * (1.f / 128.f) - mu * mu;
  float rstd = rsqrtf(var + 1e-5f);
  float y0 = (x0 - mu) * rstd * gamma[f0] + beta[f0];
  float y1 = (x1 - mu) * rstd * gamma[f1] + beta[f1];
  y0 = y0 > 0.f ? y0 : 0.1f * y0;
  y1 = y1 > 0.f ? y1 : 0.1f * y1;
  float2 o = {y0, y1};
  *(float2*)&outb[(size_t)n * DD + f0] = o;
}

// ---- Fused pooling (max+mean over contiguous sorted segments) + output GEMM ----
// One block per graph; thread t owns feature t. No atomics, no memsets.
__global__ __launch_bounds__(128) void poolout_k(const float* __restrict__ xin,
                                                 const int* __restrict__ gs,
                                                 const float* __restrict__ Wout,
                                                 const float* __restrict__ bout,
                                                 float* __restrict__ out) {
  __shared__ float sp[256];
  int g = blockIdx.x, t = threadIdx.x;
  int n0 = gs[g], n1 = gs[g + 1];
  float mx = NEG_SENT, sm = 0.f;
#pragma unroll 4
  for (int n = n0; n < n1; ++n) {
    float v = xin[(size_t)n * DD + t];
    mx = fmaxf(mx, v);
    sm += v;
  }
  float c = (float)(n1 - n0);
  sp[t] = mx;
  sp[128 + t] = sm / fmaxf(c, 1.f);
  __syncthreads();
  float acc = bout[t];
#pragma unroll 8
  for (int k = 0; k < 256; ++k) acc = __fmaf_rn(sp[k], Wout[k * 128 + t], acc);
  out[(size_t)g * 128 + t] = acc;
}

extern "C" void kernel_launch(void* const* d_in, const int* in_sizes, int n_in,
                              void* d_out, int out_size, void* d_ws, size_t ws_size,
                              hipStream_t stream) {
  const float* x       = (const float*)d_in[0];
  const int*   ei      = (const int*)d_in[1];
  const int*   batch   = (const int*)d_in[2];
  const float* W       = (const float*)d_in[3];
  const float* att_src = (const float*)d_in[4];
  const float* att_dst = (const float*)d_in[5];
  const float* bias    = (const float*)d_in[6];
  const float* gamma   = (const float*)d_in[7];
  const float* beta    = (const float*)d_in[8];
  const float* Wout    = (const float*)d_in[9];
  const float* bout    = (const float*)d_in[10];
  float* out = (float*)d_out;

  char* ws = (char*)d_ws;
  float* HB   = (float*)ws; ws += (size_t)NN * DD * 4;
  float* AB   = (float*)ws; ws += (size_t)NN * DD * 4;
  float* als  = (float*)ws; ws += (size_t)NN * HH * 4;
  float* ald  = (float*)ws; ws += (size_t)NN * HH * 4;
  int*   rp   = (int*)ws;   ws += (size_t)(NN + 1) * 4;
  int*   deg  = (int*)ws;   ws += (size_t)NN * 4;      // reused as scatter cursor
  int*   col  = (int*)ws;   ws += (size_t)ETOT * 4;
  int*   gs   = (int*)ws;   ws += (size_t)(GG + 1) * 4;
  int*   bsum = (int*)ws;   ws += (size_t)NBLK * 4;
  int*   boff = (int*)ws;   ws += (size_t)NBLK * 4;

  const int EB = (ETOT + 255) / 256;

  // ---- CSR build + graph offsets (once) ----
  hipMemsetAsync(deg, 0, (size_t)NN * 4, stream);
  deg_k<<<EB, 256, 0, stream>>>(ei, deg);
  scanA_k<<<NBLK, 256, 0, stream>>>(deg, rp, bsum);
  scanB_k<<<1, 256, 0, stream>>>(bsum, boff);
  scanC_k<<<NBLK, 256, 0, stream>>>(rp, boff, deg);
  scatter_k<<<EB, 256, 0, stream>>>(ei, deg, col);
  gstart_k<<<(GG + 1 + 63) / 64, 64, 0, stream>>>(batch, gs);

  // ---- layers ----
  const float* in = x;
  for (int l = 0; l < LL; ++l) {
    gemm_k<<<(NN + 31) / 32, 256, 0, stream>>>(in, W + (size_t)l * DD * DD, HB);
    al_k<<<(NN + 3) / 4, 256, 0, stream>>>(HB, att_src + l * DD, att_dst + l * DD, als, ald);
    agg_k<<<(NN + 3) / 4, 256, 0, stream>>>(rp, col, als, ald, HB,
                                            bias + l * DD, gamma + l * DD, beta + l * DD, AB);
    in = AB;
  }

  // ---- fused pooling + output GEMM ----
  poolout_k<<<GG, 128, 0, stream>>>(AB, gs, Wout, bout, out);
}

// Round 5
// 368.738 us; speedup vs baseline: 4.8229x; 1.3681x over previous
//
#include <hip/hip_runtime.h>

#define NN 50000
#define EE 800000
#define ETOT (EE + NN)
#define GG 256
#define LL 3
#define HH 4
#define DD 128
#define NBLK ((NN + 255) / 256)   // 196

#define NEG_SENT (-1e30f)

// float -> bf16 (round-nearest-even), finite inputs.
__device__ __forceinline__ unsigned short f2bf(float x) {
  unsigned u = __float_as_uint(x);
  unsigned r = u + 0x7FFFu + ((u >> 16) & 1u);
  return (unsigned short)(r >> 16);
}

// ---- GEMM + attention-logit epilogue ----
// h = A[N,128] @ W[128,128]; writes h as bf16 (Hb) and per-head logits
// al_s/al_d (fp32, from fp32 accumulators). 32-row tile, W staged in LDS.
__global__ __launch_bounds__(256) void gemm_al_k(const float* __restrict__ A,
                                                 const float* __restrict__ Wl,
                                                 const float* __restrict__ asrc,
                                                 const float* __restrict__ adst,
                                                 unsigned short* __restrict__ Hb,
                                                 float* __restrict__ al_s,
                                                 float* __restrict__ al_d) {
  __shared__ float sW[128 * 128];   // 64 KB
  __shared__ float sA[32][128];     // 16 KB
  int tid = threadIdx.x;
#pragma unroll
  for (int j = 0; j < 16; ++j) {
    int idx = j * 256 + tid;                 // float4 index into W
    *(float4*)&sW[idx * 4] = *(const float4*)&Wl[idx * 4];
  }
  int row0 = blockIdx.x * 32;
#pragma unroll
  for (int j = 0; j < 4; ++j) {
    int idx = j * 256 + tid;                 // float4 index into 32x128 tile
    int r = idx >> 5, c4 = idx & 31;
    int gr = row0 + r;
    float4 v = (gr < NN) ? *(const float4*)&A[(size_t)gr * DD + c4 * 4]
                         : make_float4(0.f, 0.f, 0.f, 0.f);
    *(float4*)&sA[r][c4 * 4] = v;
  }
  __syncthreads();
  int tc = tid & 31;   // col group: cols 4*tc..4*tc+3
  int tr = tid >> 5;   // row group: rows 4*tr..4*tr+3
  float acc[4][4] = {};
  for (int k = 0; k < 128; ++k) {
    float4 w = *(const float4*)&sW[k * 128 + tc * 4];
    float a[4];
#pragma unroll
    for (int r = 0; r < 4; ++r) a[r] = sA[tr * 4 + r][k];
#pragma unroll
    for (int r = 0; r < 4; ++r) {
      acc[r][0] += a[r] * w.x;
      acc[r][1] += a[r] * w.y;
      acc[r][2] += a[r] * w.z;
      acc[r][3] += a[r] * w.w;
    }
  }
  // ---- epilogue: bf16 h write + per-head logits ----
  float4 as4 = *(const float4*)&asrc[tc * 4];
  float4 ad4 = *(const float4*)&adst[tc * 4];
  int hg = tc >> 3;  // head of this column group
  float ps[4], pd[4];
#pragma unroll
  for (int r = 0; r < 4; ++r) {
    ps[r] = acc[r][0] * as4.x + acc[r][1] * as4.y + acc[r][2] * as4.z + acc[r][3] * as4.w;
    pd[r] = acc[r][0] * ad4.x + acc[r][1] * ad4.y + acc[r][2] * ad4.z + acc[r][3] * ad4.w;
  }
  // reduce over the 8 lanes sharing (tr, head)
#pragma unroll
  for (int off = 4; off; off >>= 1) {
#pragma unroll
    for (int r = 0; r < 4; ++r) {
      ps[r] += __shfl_xor(ps[r], off);
      pd[r] += __shfl_xor(pd[r], off);
    }
  }
#pragma unroll
  for (int r = 0; r < 4; ++r) {
    int gr = row0 + tr * 4 + r;
    if (gr < NN) {
      unsigned lo = (unsigned)f2bf(acc[r][0]) | ((unsigned)f2bf(acc[r][1]) << 16);
      unsigned hi = (unsigned)f2bf(acc[r][2]) | ((unsigned)f2bf(acc[r][3]) << 16);
      uint2 w = {lo, hi};
      *(uint2*)&Hb[(size_t)gr * DD + tc * 4] = w;
      if ((tc & 7) == 0) {
        al_s[gr * 4 + hg] = ps[r];
        al_d[gr * 4 + hg] = pd[r];
      }
    }
  }
}

// ---- CSR build (once per launch; reused by all 3 layers) ----
__global__ __launch_bounds__(256) void deg_k(const int* __restrict__ ei,
                                             int* __restrict__ deg) {
  int e = blockIdx.x * 256 + threadIdx.x;
  if (e >= ETOT) return;
  int d = (e < EE) ? ei[EE + e] : (e - EE);
  atomicAdd(&deg[d], 1);
}

// Device-wide exclusive scan, 3 phases, all parallel.
__global__ __launch_bounds__(256) void scanA_k(const int* __restrict__ deg,
                                               int* __restrict__ rp,
                                               int* __restrict__ bsum) {
  __shared__ int sb[256];
  int t = threadIdx.x, b = blockIdx.x, i = b * 256 + t;
  int d = (i < NN) ? deg[i] : 0;
  sb[t] = d;
  __syncthreads();
#pragma unroll
  for (int off = 1; off < 256; off <<= 1) {
    int v = (t >= off) ? sb[t - off] : 0;
    __syncthreads();
    sb[t] += v;
    __syncthreads();
  }
  if (i < NN) rp[i] = sb[t] - d;
  if (t == 255) bsum[b] = sb[255];
}

__global__ __launch_bounds__(256) void scanB_k(const int* __restrict__ bsum,
                                               int* __restrict__ boff) {
  __shared__ int sb[256];
  int t = threadIdx.x;
  int d = (t < NBLK) ? bsum[t] : 0;
  sb[t] = d;
  __syncthreads();
#pragma unroll
  for (int off = 1; off < 256; off <<= 1) {
    int v = (t >= off) ? sb[t - off] : 0;
    __syncthreads();
    sb[t] += v;
    __syncthreads();
  }
  if (t < NBLK) boff[t] = sb[t] - d;
}

__global__ __launch_bounds__(256) void scanC_k(int* __restrict__ rp,
                                               const int* __restrict__ boff,
                                               int* __restrict__ cur) {
  int b = blockIdx.x, i = b * 256 + threadIdx.x;
  if (i < NN) {
    int v = rp[i] + boff[b];
    rp[i] = v;
    cur[i] = v;
  }
  if (i == 0) rp[NN] = ETOT;
}

__global__ __launch_bounds__(256) void scatter_k(const int* __restrict__ ei,
                                                 int* __restrict__ cur,
                                                 int* __restrict__ col) {
  int e = blockIdx.x * 256 + threadIdx.x;
  if (e >= ETOT) return;
  int s, d;
  if (e < EE) { s = ei[e]; d = ei[EE + e]; }
  else        { s = e - EE; d = s; }
  int pos = atomicAdd(&cur[d], 1);
  col[pos] = s;
}

// Graph start offsets from the SORTED batch array.
__global__ __launch_bounds__(64) void gstart_k(const int* __restrict__ batch,
                                               int* __restrict__ gs) {
  int g = blockIdx.x * 64 + threadIdx.x;
  if (g > GG) return;
  int lo = 0, hi = NN;
  while (lo < hi) {
    int mid = (lo + hi) >> 1;
    if (batch[mid] < g) lo = mid + 1; else hi = mid;
  }
  gs[g] = lo;
}

// ---- Fused per-node: segment-softmax + weighted agg (bf16 gather) + bias+LN+LeakyReLU ----
__global__ __launch_bounds__(256) void agg_k(const int* __restrict__ rp,
                                             const int* __restrict__ col,
                                             const float* __restrict__ als,
                                             const float* __restrict__ ald,
                                             const unsigned short* __restrict__ Hb,
                                             const float* __restrict__ bias,
                                             const float* __restrict__ gamma,
                                             const float* __restrict__ beta,
                                             float* __restrict__ outb) {
  __shared__ float salpha[4][4][65];
  __shared__ int   scol[4][64];
  int wave = threadIdx.x >> 6, lane = threadIdx.x & 63;
  int n = blockIdx.x * 4 + wave;
  if (n >= NN) return;
  int e0 = rp[n], e1 = rp[n + 1];
  int deg = e1 - e0;
  float4 ad = *(const float4*)&ald[(size_t)n * 4];
  int hh = lane >> 4;
  float a0 = 0.f, a1 = 0.f;

  if (deg <= 64) {
    int sn = (lane < deg) ? col[e0 + lane] : -1;
    float4 as;
    if (sn >= 0) as = *(const float4*)&als[(size_t)sn * 4];
    else         as = make_float4(0.f, 0.f, 0.f, 0.f);
    float vv[4] = {as.x + ad.x, as.y + ad.y, as.z + ad.z, as.w + ad.w};
#pragma unroll
    for (int h = 0; h < 4; ++h) {
      float t = vv[h];
      t = t > 0.f ? t : 0.2f * t;
      vv[h] = (sn >= 0) ? t : NEG_SENT;
    }
    float m[4] = {vv[0], vv[1], vv[2], vv[3]};
#pragma unroll
    for (int off = 32; off; off >>= 1) {
#pragma unroll
      for (int h = 0; h < 4; ++h) m[h] = fmaxf(m[h], __shfl_xor(m[h], off));
    }
    float p[4], s[4];
#pragma unroll
    for (int h = 0; h < 4; ++h) {
      p[h] = (sn >= 0) ? __expf(vv[h] - m[h]) : 0.f;
      s[h] = p[h];
    }
#pragma unroll
    for (int off = 32; off; off >>= 1) {
#pragma unroll
      for (int h = 0; h < 4; ++h) s[h] += __shfl_xor(s[h], off);
    }
    scol[wave][lane] = sn;
#pragma unroll
    for (int h = 0; h < 4; ++h)
      salpha[wave][h][lane] = __fdividef(p[h], s[h]);
    asm volatile("s_waitcnt lgkmcnt(0)" ::: "memory");
#pragma unroll 4
    for (int j = 0; j < deg; ++j) {
      int snj = scol[wave][j];
      float alpha = salpha[wave][hh][j];
      unsigned pck = *(const unsigned*)&Hb[(size_t)snj * DD + 2 * lane];
      float h0 = __uint_as_float(pck << 16);
      float h1 = __uint_as_float(pck & 0xFFFF0000u);
      a0 = __fmaf_rn(alpha, h0, a0);
      a1 = __fmaf_rn(alpha, h1, a1);
    }
  } else {
    // fallback: online two-pass (any degree)
    float m[4] = {NEG_SENT, NEG_SENT, NEG_SENT, NEG_SENT};
    float s[4] = {0.f, 0.f, 0.f, 0.f};
    for (int e = e0 + lane; e < e1; e += 64) {
      int sn = col[e];
      float4 as = *(const float4*)&als[(size_t)sn * 4];
      float v[4] = {as.x + ad.x, as.y + ad.y, as.z + ad.z, as.w + ad.w};
#pragma unroll
      for (int h = 0; h < 4; ++h) {
        float vvv = v[h] > 0.f ? v[h] : 0.2f * v[h];
        if (vvv > m[h]) { s[h] = s[h] * __expf(m[h] - vvv) + 1.f; m[h] = vvv; }
        else             s[h] += __expf(vvv - m[h]);
      }
    }
#pragma unroll
    for (int off = 32; off; off >>= 1) {
#pragma unroll
      for (int h = 0; h < 4; ++h) {
        float mo = __shfl_xor(m[h], off);
        float so = __shfl_xor(s[h], off);
        float M = fmaxf(m[h], mo);
        s[h] = s[h] * __expf(m[h] - M) + so * __expf(mo - M);
        m[h] = M;
      }
    }
    float mh = m[hh];
    float rdh = __fdividef(1.f, s[hh]);
    float adh = (hh == 0) ? ad.x : (hh == 1) ? ad.y : (hh == 2) ? ad.z : ad.w;
    int e = e0;
    while (e < e1) {
      int cnt = min(64, e1 - e);
      int myS = (lane < cnt) ? col[e + lane] : 0;
      for (int j = 0; j < cnt; ++j) {
        int sn = __shfl(myS, j);
        float v = als[(size_t)sn * 4 + hh] + adh;
        v = v > 0.f ? v : 0.2f * v;
        float alpha = __expf(v - mh) * rdh;
        unsigned pck = *(const unsigned*)&Hb[(size_t)sn * DD + 2 * lane];
        float h0 = __uint_as_float(pck << 16);
        float h1 = __uint_as_float(pck & 0xFFFF0000u);
        a0 = __fmaf_rn(alpha, h0, a0);
        a1 = __fmaf_rn(alpha, h1, a1);
      }
      e += cnt;
    }
  }

  // bias + LayerNorm + LeakyReLU(0.1), in-register.
  int f0 = 2 * lane, f1 = 2 * lane + 1;
  float x0 = a0 + bias[f0], x1 = a1 + bias[f1];
  float sum = x0 + x1, ssq = x0 * x0 + x1 * x1;
#pragma unroll
  for (int off = 32; off; off >>= 1) {
    sum += __shfl_xor(sum, off);
    ssq += __shfl_xor(ssq, off);
  }
  float mu = sum * (1.f / 128.f);
  float var = ssq * (1.f / 128.f) - mu * mu;
  float rstd = rsqrtf(var + 1e-5f);
  float y0 = (x0 - mu) * rstd * gamma[f0] + beta[f0];
  float y1 = (x1 - mu) * rstd * gamma[f1] + beta[f1];
  y0 = y0 > 0.f ? y0 : 0.1f * y0;
  y1 = y1 > 0.f ? y1 : 0.1f * y1;
  float2 o = {y0, y1};
  *(float2*)&outb[(size_t)n * DD + f0] = o;
}

// ---- Fused pooling + output GEMM ----
__global__ __launch_bounds__(128) void poolout_k(const float* __restrict__ xin,
                                                 const int* __restrict__ gs,
                                                 const float* __restrict__ Wout,
                                                 const float* __restrict__ bout,
                                                 float* __restrict__ out) {
  __shared__ float sp[256];
  int g = blockIdx.x, t = threadIdx.x;
  int n0 = gs[g], n1 = gs[g + 1];
  float mx = NEG_SENT, sm = 0.f;
#pragma unroll 4
  for (int n = n0; n < n1; ++n) {
    float v = xin[(size_t)n * DD + t];
    mx = fmaxf(mx, v);
    sm += v;
  }
  float c = (float)(n1 - n0);
  sp[t] = mx;
  sp[128 + t] = sm / fmaxf(c, 1.f);
  __syncthreads();
  float acc = bout[t];
#pragma unroll 8
  for (int k = 0; k < 256; ++k) acc = __fmaf_rn(sp[k], Wout[k * 128 + t], acc);
  out[(size_t)g * 128 + t] = acc;
}

extern "C" void kernel_launch(void* const* d_in, const int* in_sizes, int n_in,
                              void* d_out, int out_size, void* d_ws, size_t ws_size,
                              hipStream_t stream) {
  const float* x       = (const float*)d_in[0];
  const int*   ei      = (const int*)d_in[1];
  const int*   batch   = (const int*)d_in[2];
  const float* W       = (const float*)d_in[3];
  const float* att_src = (const float*)d_in[4];
  const float* att_dst = (const float*)d_in[5];
  const float* bias    = (const float*)d_in[6];
  const float* gamma   = (const float*)d_in[7];
  const float* beta    = (const float*)d_in[8];
  const float* Wout    = (const float*)d_in[9];
  const float* bout    = (const float*)d_in[10];
  float* out = (float*)d_out;

  char* ws = (char*)d_ws;
  unsigned short* Hb = (unsigned short*)ws; ws += (size_t)NN * DD * 2;
  float* AB   = (float*)ws; ws += (size_t)NN * DD * 4;
  float* als  = (float*)ws; ws += (size_t)NN * HH * 4;
  float* ald  = (float*)ws; ws += (size_t)NN * HH * 4;
  int*   rp   = (int*)ws;   ws += (size_t)(NN + 1) * 4;
  int*   deg  = (int*)ws;   ws += (size_t)NN * 4;      // reused as scatter cursor
  int*   col  = (int*)ws;   ws += (size_t)ETOT * 4;
  int*   gs   = (int*)ws;   ws += (size_t)(GG + 1) * 4;
  int*   bsum = (int*)ws;   ws += (size_t)NBLK * 4;
  int*   boff = (int*)ws;   ws += (size_t)NBLK * 4;

  const int EB = (ETOT + 255) / 256;

  // ---- CSR build + graph offsets (once) ----
  hipMemsetAsync(deg, 0, (size_t)NN * 4, stream);
  deg_k<<<EB, 256, 0, stream>>>(ei, deg);
  scanA_k<<<NBLK, 256, 0, stream>>>(deg, rp, bsum);
  scanB_k<<<1, 256, 0, stream>>>(bsum, boff);
  scanC_k<<<NBLK, 256, 0, stream>>>(rp, boff, deg);
  scatter_k<<<EB, 256, 0, stream>>>(ei, deg, col);
  gstart_k<<<(GG + 1 + 63) / 64, 64, 0, stream>>>(batch, gs);

  // ---- layers ----
  const float* in = x;
  for (int l = 0; l < LL; ++l) {
    gemm_al_k<<<(NN + 31) / 32, 256, 0, stream>>>(in, W + (size_t)l * DD * DD,
                                                  att_src + l * DD, att_dst + l * DD,
                                                  Hb, als, ald);
    agg_k<<<(NN + 3) / 4, 256, 0, stream>>>(rp, col, als, ald, Hb,
                                            bias + l * DD, gamma + l * DD, beta + l * DD, AB);
    in = AB;
  }

  // ---- fused pooling + output GEMM ----
  poolout_k<<<GG, 128, 0, stream>>>(AB, gs, Wout, bout, out);
}

// Round 6
// 360.379 us; speedup vs baseline: 4.9348x; 1.0232x over previous
//
#include <hip/hip_runtime.h>

#define NN 50000
#define EE 800000
#define ETOT (EE + NN)
#define GG 256
#define LL 3
#define HH 4
#define DD 128
#define NBLK ((NN + 255) / 256)   // 196
#define NXCD 8
#define DPX ((NN + NXCD - 1) / NXCD)  // 6250
#define CSRB 1024                 // blocks for deg/scatter (128 per XCD group)

#define NEG_SENT (-1e30f)

// float -> bf16 (round-nearest-even), finite inputs.
__device__ __forceinline__ unsigned short f2bf(float x) {
  unsigned u = __float_as_uint(x);
  unsigned r = u + 0x7FFFu + ((u >> 16) & 1u);
  return (unsigned short)(r >> 16);
}

// ---- GEMM + attention-logit epilogue ----
__global__ __launch_bounds__(256) void gemm_al_k(const float* __restrict__ A,
                                                 const float* __restrict__ Wl,
                                                 const float* __restrict__ asrc,
                                                 const float* __restrict__ adst,
                                                 unsigned short* __restrict__ Hb,
                                                 float* __restrict__ al_s,
                                                 float* __restrict__ al_d) {
  __shared__ float sW[128 * 128];   // 64 KB
  __shared__ float sA[32][128];     // 16 KB
  int tid = threadIdx.x;
#pragma unroll
  for (int j = 0; j < 16; ++j) {
    int idx = j * 256 + tid;
    *(float4*)&sW[idx * 4] = *(const float4*)&Wl[idx * 4];
  }
  int row0 = blockIdx.x * 32;
#pragma unroll
  for (int j = 0; j < 4; ++j) {
    int idx = j * 256 + tid;
    int r = idx >> 5, c4 = idx & 31;
    int gr = row0 + r;
    float4 v = (gr < NN) ? *(const float4*)&A[(size_t)gr * DD + c4 * 4]
                         : make_float4(0.f, 0.f, 0.f, 0.f);
    *(float4*)&sA[r][c4 * 4] = v;
  }
  __syncthreads();
  int tc = tid & 31;
  int tr = tid >> 5;
  float acc[4][4] = {};
  for (int k = 0; k < 128; ++k) {
    float4 w = *(const float4*)&sW[k * 128 + tc * 4];
    float a[4];
#pragma unroll
    for (int r = 0; r < 4; ++r) a[r] = sA[tr * 4 + r][k];
#pragma unroll
    for (int r = 0; r < 4; ++r) {
      acc[r][0] += a[r] * w.x;
      acc[r][1] += a[r] * w.y;
      acc[r][2] += a[r] * w.z;
      acc[r][3] += a[r] * w.w;
    }
  }
  float4 as4 = *(const float4*)&asrc[tc * 4];
  float4 ad4 = *(const float4*)&adst[tc * 4];
  int hg = tc >> 3;
  float ps[4], pd[4];
#pragma unroll
  for (int r = 0; r < 4; ++r) {
    ps[r] = acc[r][0] * as4.x + acc[r][1] * as4.y + acc[r][2] * as4.z + acc[r][3] * as4.w;
    pd[r] = acc[r][0] * ad4.x + acc[r][1] * ad4.y + acc[r][2] * ad4.z + acc[r][3] * ad4.w;
  }
#pragma unroll
  for (int off = 4; off; off >>= 1) {
#pragma unroll
    for (int r = 0; r < 4; ++r) {
      ps[r] += __shfl_xor(ps[r], off);
      pd[r] += __shfl_xor(pd[r], off);
    }
  }
#pragma unroll
  for (int r = 0; r < 4; ++r) {
    int gr = row0 + tr * 4 + r;
    if (gr < NN) {
      unsigned lo = (unsigned)f2bf(acc[r][0]) | ((unsigned)f2bf(acc[r][1]) << 16);
      unsigned hi = (unsigned)f2bf(acc[r][2]) | ((unsigned)f2bf(acc[r][3]) << 16);
      uint2 w = {lo, hi};
      *(uint2*)&Hb[(size_t)gr * DD + tc * 4] = w;
      if ((tc & 7) == 0) {
        al_s[gr * 4 + hg] = ps[r];
        al_d[gr * 4 + hg] = pd[r];
      }
    }
  }
}

// ---- CSR build: XCD-affine dst-range partitioning ----
// blockIdx%8 selects a dst range; that group's atomics+writes stay in one
// XCD's L2 (blockIdx round-robins across XCDs). Union of ranges covers all
// edges exactly once, so correctness holds for any block->XCD mapping.
__global__ __launch_bounds__(256) void deg_k(const int* __restrict__ ei,
                                             int* __restrict__ deg) {
  int lo = (blockIdx.x & 7) * DPX, hi = lo + DPX;
  int stride = (gridDim.x >> 3) * 256;
  for (int e = (blockIdx.x >> 3) * 256 + threadIdx.x; e < ETOT; e += stride) {
    int d = (e < EE) ? ei[EE + e] : (e - EE);
    if (d >= lo && d < hi) atomicAdd(&deg[d], 1);
  }
}

// Device-wide exclusive scan, 3 phases.
__global__ __launch_bounds__(256) void scanA_k(const int* __restrict__ deg,
                                               int* __restrict__ rp,
                                               int* __restrict__ bsum) {
  __shared__ int sb[256];
  int t = threadIdx.x, b = blockIdx.x, i = b * 256 + t;
  int d = (i < NN) ? deg[i] : 0;
  sb[t] = d;
  __syncthreads();
#pragma unroll
  for (int off = 1; off < 256; off <<= 1) {
    int v = (t >= off) ? sb[t - off] : 0;
    __syncthreads();
    sb[t] += v;
    __syncthreads();
  }
  if (i < NN) rp[i] = sb[t] - d;
  if (t == 255) bsum[b] = sb[255];
}

__global__ __launch_bounds__(256) void scanB_k(const int* __restrict__ bsum,
                                               int* __restrict__ boff) {
  __shared__ int sb[256];
  int t = threadIdx.x;
  int d = (t < NBLK) ? bsum[t] : 0;
  sb[t] = d;
  __syncthreads();
#pragma unroll
  for (int off = 1; off < 256; off <<= 1) {
    int v = (t >= off) ? sb[t - off] : 0;
    __syncthreads();
    sb[t] += v;
    __syncthreads();
  }
  if (t < NBLK) boff[t] = sb[t] - d;
}

__global__ __launch_bounds__(256) void scanC_k(int* __restrict__ rp,
                                               const int* __restrict__ boff,
                                               int* __restrict__ cur) {
  int b = blockIdx.x, i = b * 256 + threadIdx.x;
  if (i < NN) {
    int v = rp[i] + boff[b];
    rp[i] = v;
    cur[i] = v;
  }
  if (i == 0) rp[NN] = ETOT;
}

__global__ __launch_bounds__(256) void scatter_k(const int* __restrict__ ei,
                                                 int* __restrict__ cur,
                                                 int* __restrict__ col) {
  int lo = (blockIdx.x & 7) * DPX, hi = lo + DPX;
  int stride = (gridDim.x >> 3) * 256;
  for (int e = (blockIdx.x >> 3) * 256 + threadIdx.x; e < ETOT; e += stride) {
    int s, d;
    if (e < EE) { s = ei[e]; d = ei[EE + e]; }
    else        { s = e - EE; d = s; }
    if (d >= lo && d < hi) {
      int pos = atomicAdd(&cur[d], 1);
      col[pos] = s;
    }
  }
}

// Graph start offsets from the SORTED batch array.
__global__ __launch_bounds__(64) void gstart_k(const int* __restrict__ batch,
                                               int* __restrict__ gs) {
  int g = blockIdx.x * 64 + threadIdx.x;
  if (g > GG) return;
  int lo = 0, hi = NN;
  while (lo < hi) {
    int mid = (lo + hi) >> 1;
    if (batch[mid] < g) lo = mid + 1; else hi = mid;
  }
  gs[g] = lo;
}

// ---- Fused per-node: segment-softmax + weighted agg (bf16 gather) + bias+LN+LeakyReLU ----
__global__ __launch_bounds__(256) void agg_k(const int* __restrict__ rp,
                                             const int* __restrict__ col,
                                             const float* __restrict__ als,
                                             const float* __restrict__ ald,
                                             const unsigned short* __restrict__ Hb,
                                             const float* __restrict__ bias,
                                             const float* __restrict__ gamma,
                                             const float* __restrict__ beta,
                                             float* __restrict__ outb) {
  __shared__ float salpha[4][4][65];
  __shared__ int   scol[4][64];
  int wave = threadIdx.x >> 6, lane = threadIdx.x & 63;
  int n = blockIdx.x * 4 + wave;
  if (n >= NN) return;
  int e0 = rp[n], e1 = rp[n + 1];
  int deg = e1 - e0;
  float4 ad = *(const float4*)&ald[(size_t)n * 4];
  int hh = lane >> 4;
  float a0 = 0.f, a1 = 0.f;

  if (deg <= 64) {
    int sn = (lane < deg) ? col[e0 + lane] : -1;
    float4 as;
    if (sn >= 0) as = *(const float4*)&als[(size_t)sn * 4];
    else         as = make_float4(0.f, 0.f, 0.f, 0.f);
    float vv[4] = {as.x + ad.x, as.y + ad.y, as.z + ad.z, as.w + ad.w};
#pragma unroll
    for (int h = 0; h < 4; ++h) {
      float t = vv[h];
      t = t > 0.f ? t : 0.2f * t;
      vv[h] = (sn >= 0) ? t : NEG_SENT;
    }
    float m[4] = {vv[0], vv[1], vv[2], vv[3]};
#pragma unroll
    for (int off = 32; off; off >>= 1) {
#pragma unroll
      for (int h = 0; h < 4; ++h) m[h] = fmaxf(m[h], __shfl_xor(m[h], off));
    }
    float p[4], s[4];
#pragma unroll
    for (int h = 0; h < 4; ++h) {
      p[h] = (sn >= 0) ? __expf(vv[h] - m[h]) : 0.f;
      s[h] = p[h];
    }
#pragma unroll
    for (int off = 32; off; off >>= 1) {
#pragma unroll
      for (int h = 0; h < 4; ++h) s[h] += __shfl_xor(s[h], off);
    }
    scol[wave][lane] = sn;
#pragma unroll
    for (int h = 0; h < 4; ++h)
      salpha[wave][h][lane] = __fdividef(p[h], s[h]);
    asm volatile("s_waitcnt lgkmcnt(0)" ::: "memory");
#pragma unroll 4
    for (int j = 0; j < deg; ++j) {
      int snj = scol[wave][j];
      float alpha = salpha[wave][hh][j];
      unsigned pck = *(const unsigned*)&Hb[(size_t)snj * DD + 2 * lane];
      float h0 = __uint_as_float(pck << 16);
      float h1 = __uint_as_float(pck & 0xFFFF0000u);
      a0 = __fmaf_rn(alpha, h0, a0);
      a1 = __fmaf_rn(alpha, h1, a1);
    }
  } else {
    float m[4] = {NEG_SENT, NEG_SENT, NEG_SENT, NEG_SENT};
    float s[4] = {0.f, 0.f, 0.f, 0.f};
    for (int e = e0 + lane; e < e1; e += 64) {
      int sn = col[e];
      float4 as = *(const float4*)&als[(size_t)sn * 4];
      float v[4] = {as.x + ad.x, as.y + ad.y, as.z + ad.z, as.w + ad.w};
#pragma unroll
      for (int h = 0; h < 4; ++h) {
        float vvv = v[h] > 0.f ? v[h] : 0.2f * v[h];
        if (vvv > m[h]) { s[h] = s[h] * __expf(m[h] - vvv) + 1.f; m[h] = vvv; }
        else             s[h] += __expf(vvv - m[h]);
      }
    }
#pragma unroll
    for (int off = 32; off; off >>= 1) {
#pragma unroll
      for (int h = 0; h < 4; ++h) {
        float mo = __shfl_xor(m[h], off);
        float so = __shfl_xor(s[h], off);
        float M = fmaxf(m[h], mo);
        s[h] = s[h] * __expf(m[h] - M) + so * __expf(mo - M);
        m[h] = M;
      }
    }
    float mh = m[hh];
    float rdh = __fdividef(1.f, s[hh]);
    float adh = (hh == 0) ? ad.x : (hh == 1) ? ad.y : (hh == 2) ? ad.z : ad.w;
    int e = e0;
    while (e < e1) {
      int cnt = min(64, e1 - e);
      int myS = (lane < cnt) ? col[e + lane] : 0;
      for (int j = 0; j < cnt; ++j) {
        int sn = __shfl(myS, j);
        float v = als[(size_t)sn * 4 + hh] + adh;
        v = v > 0.f ? v : 0.2f * v;
        float alpha = __expf(v - mh) * rdh;
        unsigned pck = *(const unsigned*)&Hb[(size_t)sn * DD + 2 * lane];
        float h0 = __uint_as_float(pck << 16);
        float h1 = __uint_as_float(pck & 0xFFFF0000u);
        a0 = __fmaf_rn(alpha, h0, a0);
        a1 = __fmaf_rn(alpha, h1, a1);
      }
      e += cnt;
    }
  }

  int f0 = 2 * lane, f1 = 2 * lane + 1;
  float x0 = a0 + bias[f0], x1 = a1 + bias[f1];
  float sum = x0 + x1, ssq = x0 * x0 + x1 * x1;
#pragma unroll
  for (int off = 32; off; off >>= 1) {
    sum += __shfl_xor(sum, off);
    ssq += __shfl_xor(ssq, off);
  }
  float mu = sum * (1.f / 128.f);
  float var = ssq * (1.f / 128.f) - mu * mu;
  float rstd = rsqrtf(var + 1e-5f);
  float y0 = (x0 - mu) * rstd * gamma[f0] + beta[f0];
  float y1 = (x1 - mu) * rstd * gamma[f1] + beta[f1];
  y0 = y0 > 0.f ? y0 : 0.1f * y0;
  y1 = y1 > 0.f ? y1 : 0.1f * y1;
  float2 o = {y0, y1};
  *(float2*)&outb[(size_t)n * DD + f0] = o;
}

// ---- Fused pooling + output GEMM ----
__global__ __launch_bounds__(128) void poolout_k(const float* __restrict__ xin,
                                                 const int* __restrict__ gs,
                                                 const float* __restrict__ Wout,
                                                 const float* __restrict__ bout,
                                                 float* __restrict__ out) {
  __shared__ float sp[256];
  int g = blockIdx.x, t = threadIdx.x;
  int n0 = gs[g], n1 = gs[g + 1];
  float mx = NEG_SENT, sm = 0.f;
#pragma unroll 4
  for (int n = n0; n < n1; ++n) {
    float v = xin[(size_t)n * DD + t];
    mx = fmaxf(mx, v);
    sm += v;
  }
  float c = (float)(n1 - n0);
  sp[t] = mx;
  sp[128 + t] = sm / fmaxf(c, 1.f);
  __syncthreads();
  float acc = bout[t];
#pragma unroll 8
  for (int k = 0; k < 256; ++k) acc = __fmaf_rn(sp[k], Wout[k * 128 + t], acc);
  out[(size_t)g * 128 + t] = acc;
}

extern "C" void kernel_launch(void* const* d_in, const int* in_sizes, int n_in,
                              void* d_out, int out_size, void* d_ws, size_t ws_size,
                              hipStream_t stream) {
  const float* x       = (const float*)d_in[0];
  const int*   ei      = (const int*)d_in[1];
  const int*   batch   = (const int*)d_in[2];
  const float* W       = (const float*)d_in[3];
  const float* att_src = (const float*)d_in[4];
  const float* att_dst = (const float*)d_in[5];
  const float* bias    = (const float*)d_in[6];
  const float* gamma   = (const float*)d_in[7];
  const float* beta    = (const float*)d_in[8];
  const float* Wout    = (const float*)d_in[9];
  const float* bout    = (const float*)d_in[10];
  float* out = (float*)d_out;

  char* ws = (char*)d_ws;
  unsigned short* Hb = (unsigned short*)ws; ws += (size_t)NN * DD * 2;
  float* AB   = (float*)ws; ws += (size_t)NN * DD * 4;
  float* als  = (float*)ws; ws += (size_t)NN * HH * 4;
  float* ald  = (float*)ws; ws += (size_t)NN * HH * 4;
  int*   rp   = (int*)ws;   ws += (size_t)(NN + 1) * 4;
  int*   deg  = (int*)ws;   ws += (size_t)NN * 4;      // reused as scatter cursor
  int*   col  = (int*)ws;   ws += (size_t)ETOT * 4;
  int*   gs   = (int*)ws;   ws += (size_t)(GG + 1) * 4;
  int*   bsum = (int*)ws;   ws += (size_t)NBLK * 4;
  int*   boff = (int*)ws;   ws += (size_t)NBLK * 4;

  // ---- CSR build + graph offsets (once) ----
  hipMemsetAsync(deg, 0, (size_t)NN * 4, stream);
  deg_k<<<CSRB, 256, 0, stream>>>(ei, deg);
  scanA_k<<<NBLK, 256, 0, stream>>>(deg, rp, bsum);
  scanB_k<<<1, 256, 0, stream>>>(bsum, boff);
  scanC_k<<<NBLK, 256, 0, stream>>>(rp, boff, deg);
  scatter_k<<<CSRB, 256, 0, stream>>>(ei, deg, col);
  gstart_k<<<(GG + 1 + 63) / 64, 64, 0, stream>>>(batch, gs);

  // ---- layers ----
  const float* in = x;
  for (int l = 0; l < LL; ++l) {
    gemm_al_k<<<(NN + 31) / 32, 256, 0, stream>>>(in, W + (size_t)l * DD * DD,
                                                  att_src + l * DD, att_dst + l * DD,
                                                  Hb, als, ald);
    agg_k<<<(NN + 3) / 4, 256, 0, stream>>>(rp, col, als, ald, Hb,
                                            bias + l * DD, gamma + l * DD, beta + l * DD, AB);
    in = AB;
  }

  // ---- fused pooling + output GEMM ----
  poolout_k<<<GG, 128, 0, stream>>>(AB, gs, Wout, bout, out);
}